// Round 4
// baseline (754.702 us; speedup 1.0000x reference)
//
#include <hip/hip_runtime.h>
#include <cmath>

#define HW 307200        // 480*640
#define NB 8             // batches
#define NBASE 63         // input basis channels (ones channel prepended -> 64)
#define NCHUNK (HW/256)  // 1200 pixel chunks of 256
#define GRAM_BLKS 96     // 96*8 = 768 blocks = exactly 3 per CU

// ---- workspace layout (floats) ----
#define XTY_OFF 0                        // 8 * 64
#define YTY_OFF (NB*64)                  // 8
#define NC_OFF  (YTY_OFF + NB)           // 8
#define ZERO_FLOATS (NC_OFF + NB)        // atomic-accumulated region ends here (528)
#define XTX_OFF ZERO_FLOATS              // 8 * 64*64 (written whole by reduce_kernel)
#define MP_OFF  (XTX_OFF + NB*64*64)     // 8 * 64*64 (upper-tri M, diag halved, /beta)
#define WV_OFF  (MP_OFF + NB*64*64)      // 8 * 64

// ---- output layout (floats) ----
#define OUT_W   (NB*HW)                  // weights after logits
#define OUT_VAR (OUT_W + NB*64)          // var after weights
// NOTE: gram partials (8*96*4096 floats = 12.6MB) are staged in out[], consumed
// by reduce_kernel BEFORE solve/predvar overwrite out. Stream-ordered.

__device__ __forceinline__ bool finitef(float x) {
    // fast-math-proof isfinite: exponent bits not all ones
    return (__float_as_uint(x) & 0x7f800000u) != 0x7f800000u;
}

// ============================================================
// Kernel 1: sparse masked Gram, STREAM-ORDER fetch + COMPACT compute.
// Per 256-px chunk: ballot-prefix assigns each valid pixel a slot in a
// 64-row tile. Threads (quad q = t&63, channel-group cg = t>>6) load the
// chunk's basis values as float4 quads ONLY if the quad holds a pixel in
// the current tile window (sequential-line predicated fetch ~56% of lines),
// scatter them into tile[row][ch], and when a window fills run the dense
// 8x8 register-tile outer product (compute stays at the ~5% valid level).
// Per-wave accs LDS-reduced; one coalesced 16KB partial per block.
// ============================================================
__global__ __launch_bounds__(256) void gram_kernel(
    const float* __restrict__ bases, const float* __restrict__ targets,
    float* __restrict__ ws, float* __restrict__ part)
{
    __shared__ float tile[64*68];   // [row][channel], stride 68; tail reused for Xty reduce
    __shared__ float sy[64];        // y per tile row
    __shared__ float yv[256];       // chunk targets
    __shared__ int   smap[256];     // chunk-pos -> tile slot (or -1)
    __shared__ int   wcnt[4];       // per-wave valid counts

    const int t  = threadIdx.x;
    const int b  = blockIdx.y;
    const int wv = t >> 6;          // wave id 0..3
    const int l  = t & 63;          // lane
    const int ti = l >> 3, tj = l & 7;
    const int q  = l;               // pixel-quad 0..63 (pixels 4q..4q+3 of chunk)
    const int cg = wv;              // channel group 0..3

    float acc[8][8];
#pragma unroll
    for (int i = 0; i < 8; i++)
#pragma unroll
        for (int j = 0; j < 8; j++) acc[i][j] = 0.f;
    float acc_xty = 0.f, acc_yty = 0.f, acc_n = 0.f;

    const float* __restrict__ basesb = bases + (long)b * NBASE * HW;
    const float* __restrict__ targb  = targets + (long)b * HW;

    auto compute_tile = [&]() {
#pragma unroll 2
        for (int pp = 0; pp < 16; ++pp) {
            const int p2 = wv * 16 + pp;
            const float4 r0 = *(const float4*)&tile[p2*68 + 8*ti];
            const float4 r1 = *(const float4*)&tile[p2*68 + 8*ti + 4];
            const float4 c0 = *(const float4*)&tile[p2*68 + 8*tj];
            const float4 c1 = *(const float4*)&tile[p2*68 + 8*tj + 4];
            const float rr[8] = {r0.x,r0.y,r0.z,r0.w,r1.x,r1.y,r1.z,r1.w};
            const float cc[8] = {c0.x,c0.y,c0.z,c0.w,c1.x,c1.y,c1.z,c1.w};
#pragma unroll
            for (int i = 0; i < 8; i++)
#pragma unroll
                for (int j = 0; j < 8; j++)
                    acc[i][j] = fmaf(rr[i], cc[j], acc[i][j]);
            // Xty: lane l owns channel l
            acc_xty = fmaf(sy[p2], tile[p2*68 + l], acc_xty);
        }
    };

    int tilefill = 0;               // rows currently occupied (block-uniform)

    for (int j = blockIdx.x; j < NCHUNK; j += GRAM_BLKS) {
        const int pix0 = j * 256;
        // ---- append: coalesced target read, ballot-prefix slot assignment ----
        const float y = targb[pix0 + t];
        const bool fin = finitef(y);
        if (fin) { acc_yty = fmaf(y, y, acc_yty); acc_n += 1.f; }
        const unsigned long long m = __ballot(fin);
        if (l == 0) wcnt[wv] = __popcll(m);
        yv[t] = y;
        __syncthreads();
        int pre = tilefill;
        for (int w2 = 0; w2 < wv; ++w2) pre += wcnt[w2];
        const int rank = __popcll(m & ((1ull << l) - 1ull));
        smap[t] = fin ? (pre + rank) : -1;
        const int vc = wcnt[0] + wcnt[1] + wcnt[2] + wcnt[3];
        __syncthreads();

        // this thread's quad: slots + targets
        int   sreg[4]; float yreg[4];
#pragma unroll
        for (int i = 0; i < 4; i++) {
            sreg[i] = smap[4*q + i];
            yreg[i] = yv[4*q + i];
        }

        // ---- window loop: fill tile (register-transient loads), flush when full ----
        const int nwin = (tilefill + vc) >> 6;
        for (int w = 0; w <= nwin; ++w) {
            const bool doW = ((sreg[0] >= 0) & ((sreg[0] >> 6) == w)) |
                             ((sreg[1] >= 0) & ((sreg[1] >> 6) == w)) |
                             ((sreg[2] >= 0) & ((sreg[2] >> 6) == w)) |
                             ((sreg[3] >= 0) & ((sreg[3] >> 6) == w));
            if (doW) {
#pragma unroll
                for (int k = 0; k < 16; k++) {
                    const int cb = cg + 4*k;       // basis channel 0..62; 63 = ones marker
                    float4 v = make_float4(0.f, 0.f, 0.f, 0.f);
                    if (cb < 63)
                        v = *(const float4*)&basesb[(long)cb * HW + pix0 + 4*q];
#pragma unroll
                    for (int i = 0; i < 4; i++) {
                        const int s = sreg[i];
                        if (s >= 0 && (s >> 6) == w) {
                            const int row = s & 63;
                            const float vi = (i == 0) ? v.x : (i == 1) ? v.y
                                           : (i == 2) ? v.z : v.w;
                            if (cb < 63) {
                                tile[row*68 + cb + 1] = vi;
                            } else {                // cg==3, k==15: ones channel + y
                                tile[row*68] = 1.f;
                                sy[row] = yreg[i];
                            }
                        }
                    }
                }
            }
            __syncthreads();
            if (w < nwin) { compute_tile(); __syncthreads(); }
        }
        tilefill = (tilefill + vc) & 63;
    }

    // ---- final flush: zero-pad rows tilefill..63, compute ----
    if (tilefill > 0) {
        for (int r = tilefill + wv; r < 64; r += 4) {
            tile[r*68 + l] = 0.f;
            if (l == 0) sy[r] = 0.f;
        }
        __syncthreads();
        compute_tile();
    }
    __syncthreads();

    // ---- cross-wave reduce of acc tiles into tile[0..4096) ----
    for (int w = 0; w < 4; ++w) {
        if (wv == w) {
#pragma unroll
            for (int i = 0; i < 8; i++)
#pragma unroll
                for (int j2 = 0; j2 < 8; j2++) {
                    const int e = (8*ti + i) * 64 + 8*tj + j2;
                    tile[e] = (w == 0) ? acc[i][j2] : tile[e] + acc[i][j2];
                }
        }
        __syncthreads();
    }
    // one coalesced 16KB partial per block, no atomics
    float* __restrict__ pb = part + (long)(b * GRAM_BLKS + blockIdx.x) * 4096;
#pragma unroll
    for (int k = 0; k < 4; ++k)
        *(float4*)&pb[t*16 + 4*k] = *(const float4*)&tile[t*16 + 4*k];

    // Xty: cross-wave reduce into tile[4096..4160), then 64 atomics/block
    for (int w = 0; w < 4; ++w) {
        if (wv == w) tile[4096 + l] = (w == 0) ? acc_xty : tile[4096 + l] + acc_xty;
        __syncthreads();
    }
    if (t < 64) atomicAdd(&ws[XTY_OFF + b*64 + t], tile[4096 + t]);

    // yty, N: wave shuffle reduce + one atomic per wave
#pragma unroll
    for (int off = 32; off; off >>= 1) {
        acc_yty += __shfl_down(acc_yty, off, 64);
        acc_n   += __shfl_down(acc_n,   off, 64);
    }
    if (l == 0) {
        atomicAdd(&ws[YTY_OFF + b], acc_yty);
        atomicAdd(&ws[NC_OFF  + b], acc_n);
    }
}

// ============================================================
// Kernel 1b: sum the 96 per-block XtX partials -> ws (coalesced)
// ============================================================
__global__ __launch_bounds__(256) void reduce_kernel(
    const float* __restrict__ part, float* __restrict__ ws)
{
    const int b = blockIdx.y;
    const int e = blockIdx.x * 256 + threadIdx.x;   // grid.x = 16 -> e in [0,4096)
    const float* __restrict__ pb = part + (long)b * GRAM_BLKS * 4096 + e;
    float s = 0.f;
#pragma unroll 8
    for (int k = 0; k < GRAM_BLKS; ++k)
        s += pb[(long)k * 4096];
    ws[XTX_OFF + b*4096 + e] = s;
}

// ============================================================
// Kernel 2: per batch, 64 threads = 1 wave (barriers ~free).
// Cholesky in LDS; explicit inverse with the W-column held in 64
// REGISTERS (fully unrolled, static indices) and L rows read as
// wave-uniform LDS broadcasts; one reciprocal per row instead of
// per-element divides. Mp emitted by COLUMN (thread t = column t,
// coalesced; W[j][t] = Wc[j], no symmetry assumption).
// ============================================================
__global__ __launch_bounds__(64) void solve_kernel(
    float* __restrict__ ws, float* __restrict__ out)
{
    __shared__ float A[64*65];
    __shared__ float d0[64], dinv_s[64], xty_s[64], wv_s[64];

    const int b = blockIdx.x;
    const int t = threadIdx.x;
    const float* XtX = ws + XTX_OFF + b * 4096;

    for (int e = t; e < 4096; e += 64)
        A[(e >> 6) * 65 + (e & 63)] = XtX[e];
    xty_s[t] = ws[XTY_OFF + b*64 + t];
    const float yty = ws[YTY_OFF + b];
    const float Nc  = ws[NC_OFF  + b];
    __syncthreads();
    d0[t] = A[t*65 + t];
    __syncthreads();

    // Cholesky (lower), upper triangle keeps original XtX
    for (int k = 0; k < 64; k++) {
        const float akk = A[k*65 + k];
        __syncthreads();
        const float dk = sqrtf(akk);
        if (t == k)      A[k*65 + k] = dk;
        else if (t > k)  A[t*65 + k] /= dk;
        __syncthreads();
        if (t > k) {
            const float ltk = A[t*65 + k];
            for (int j = k + 1; j <= t; j++)
                A[t*65 + j] -= ltk * A[j*65 + k];
        }
        __syncthreads();
    }

    dinv_s[t] = 1.f / A[t*65 + t];
    __syncthreads();

    // W = (L L^T)^-1, column t in registers
    float Wc[64];
    // forward: L Y = e_t
#pragma unroll
    for (int i = 0; i < 64; i++) {
        float s0 = (i == t) ? 1.f : 0.f, s1 = 0.f, s2 = 0.f, s3 = 0.f;
        const int nfull = i >> 2;
#pragma unroll
        for (int qd = 0; qd < nfull; qd++) {
            const int j = qd * 4;
            s0 = fmaf(-A[i*65 + j    ], Wc[j    ], s0);
            s1 = fmaf(-A[i*65 + j + 1], Wc[j + 1], s1);
            s2 = fmaf(-A[i*65 + j + 2], Wc[j + 2], s2);
            s3 = fmaf(-A[i*65 + j + 3], Wc[j + 3], s3);
        }
#pragma unroll
        for (int j = nfull * 4; j < i; j++)
            s0 = fmaf(-A[i*65 + j], Wc[j], s0);
        Wc[i] = ((s0 + s1) + (s2 + s3)) * dinv_s[i];
    }
    // backward: L^T W = Y
#pragma unroll
    for (int i = 63; i >= 0; i--) {
        float s0 = Wc[i], s1 = 0.f, s2 = 0.f, s3 = 0.f;
        const int j0 = i + 1;
        const int nfull = (64 - j0) >> 2;
#pragma unroll
        for (int qd = 0; qd < nfull; qd++) {
            const int j = j0 + qd * 4;
            s0 = fmaf(-A[(j    )*65 + i], Wc[j    ], s0);
            s1 = fmaf(-A[(j + 1)*65 + i], Wc[j + 1], s1);
            s2 = fmaf(-A[(j + 2)*65 + i], Wc[j + 2], s2);
            s3 = fmaf(-A[(j + 3)*65 + i], Wc[j + 3], s3);
        }
#pragma unroll
        for (int j = j0 + nfull * 4; j < 64; j++)
            s0 = fmaf(-A[j*65 + i], Wc[j], s0);
        Wc[i] = ((s0 + s1) + (s2 + s3)) * dinv_s[i];
    }

    // w_t = sum_j W[j][t] * xty[j]  (= (W xty)_t, W symmetric)
    float w0 = 0.f, w1 = 0.f, w2 = 0.f, w3 = 0.f;
#pragma unroll
    for (int j = 0; j < 64; j += 4) {
        w0 = fmaf(Wc[j    ], xty_s[j    ], w0);
        w1 = fmaf(Wc[j + 1], xty_s[j + 1], w1);
        w2 = fmaf(Wc[j + 2], xty_s[j + 2], w2);
        w3 = fmaf(Wc[j + 3], xty_s[j + 3], w3);
    }
    const float wt = (w0 + w1) + (w2 + w3);
    wv_s[t] = wt;
    __syncthreads();

    // E_d = yty - 2 w.Xty + w.(XtX w)  (XtX from upper triangle + saved diag)
    float qt = 0.f;
#pragma unroll
    for (int j = 0; j < 64; j++) {
        const float x = (j > t) ? A[t*65 + j] : ((j == t) ? d0[t] : A[j*65 + t]);
        qt = fmaf(x, wv_s[j], qt);
    }
    float r1 = wt * xty_s[t];
    float r2 = wt * qt;
#pragma unroll
    for (int off = 32; off; off >>= 1) {
        r1 += __shfl_down(r1, off, 64);
        r2 += __shfl_down(r2, off, 64);
    }
    r1 = __shfl(r1, 0, 64);
    r2 = __shfl(r2, 0, 64);
    const float E_d = yty - 2.f * r1 + r2;

    // EM beta loop (uniform on all lanes), faithful to reference latch order
    float beta0 = sqrtf(Nc);
    float beta  = beta0;
    bool  done  = false;
#pragma unroll
    for (int it = 0; it < 5; ++it) {
        const float Tr_d = 64.f / beta;
        const float beta_new = Nc / (E_d + Tr_d);
        const bool conv = fabsf(beta_new / beta0 - 1.f) < 0.02f;
        if (!done) { beta = beta_new; beta0 = beta_new; }
        done = done || conv;
    }
    const float ib = 1.f / beta;

    out[OUT_W + b*64 + t] = wt;
    ws[WV_OFF + b*64 + t] = wt;
    // Mp[row j][col t]: zero below diag, 0.5x diag, * 1/beta. Coalesced column write.
    float* __restrict__ Mp = ws + MP_OFF + b * 4096;
#pragma unroll
    for (int j = 0; j < 64; j++) {
        const float v = (j > t) ? 0.f : ((j == t) ? 0.5f : 1.f) * Wc[j] * ib;
        Mp[j*64 + t] = v;
    }
}

// ============================================================
// Kernel 3: 2 pixels/thread: pred = w.b, var = 2*sum_i b_i*sum_{j>=i} Mp[i][j] b_j
// Mp staged in LDS (16KB), wave-uniform ds_read_b128 broadcasts.
// ============================================================
__global__ __launch_bounds__(256, 2) void predvar_kernel(
    const float* __restrict__ bases, const float* __restrict__ ws,
    float* __restrict__ out)
{
    __shared__ float Mp_s[4096];
    __shared__ float w_s[64];

    const int b = blockIdx.y;
    const int t = threadIdx.x;
    {
        const float4* __restrict__ src = (const float4*)(ws + MP_OFF + b * 4096);
        float4* dst = (float4*)Mp_s;
        for (int e = t; e < 1024; e += 256) dst[e] = src[e];
        if (t < 64) w_s[t] = ws[WV_OFF + b*64 + t];
    }
    __syncthreads();

    const int pix = (blockIdx.x * 256 + t) * 2;
    const float* basesb = bases + (long)b * NBASE * HW + pix;

    float2 bv[64];
    bv[0] = make_float2(1.f, 1.f);
#pragma unroll
    for (int c = 1; c < 64; c++)
        bv[c] = *(const float2*)&basesb[(long)(c - 1) * HW];

    float px = w_s[0], py = w_s[0];
#pragma unroll
    for (int c = 1; c < 64; c++) {
        px = fmaf(w_s[c], bv[c].x, px);
        py = fmaf(w_s[c], bv[c].y, py);
    }

    float vx = 0.f, vy = 0.f;
#pragma unroll
    for (int i = 0; i < 64; i++) {
        float sx = 0.f, sy2 = 0.f;
#pragma unroll
        for (int qd = i >> 2; qd < 16; qd++) {
            const float4 m = *(const float4*)&Mp_s[i*64 + 4*qd];
            sx  = fmaf(m.x, bv[4*qd+0].x, sx);
            sy2 = fmaf(m.x, bv[4*qd+0].y, sy2);
            sx  = fmaf(m.y, bv[4*qd+1].x, sx);
            sy2 = fmaf(m.y, bv[4*qd+1].y, sy2);
            sx  = fmaf(m.z, bv[4*qd+2].x, sx);
            sy2 = fmaf(m.z, bv[4*qd+2].y, sy2);
            sx  = fmaf(m.w, bv[4*qd+3].x, sx);
            sy2 = fmaf(m.w, bv[4*qd+3].y, sy2);
        }
        vx = fmaf(sx,  bv[i].x, vx);
        vy = fmaf(sy2, bv[i].y, vy);
    }

    *(float2*)&out[(long)b * HW + pix] = make_float2(px, py);
    *(float2*)&out[OUT_VAR + (long)b * HW + pix] = make_float2(2.f * vx, 2.f * vy);
}

extern "C" void kernel_launch(void* const* d_in, const int* in_sizes, int n_in,
                              void* d_out, int out_size, void* d_ws, size_t ws_size,
                              hipStream_t stream)
{
    const float* bases   = (const float*)d_in[0];
    const float* targets = (const float*)d_in[1];
    float* out = (float*)d_out;
    float* ws  = (float*)d_ws;

    // zero only the atomic-accumulated region (Xty/yty/N); XtX is written whole
    hipMemsetAsync(d_ws, 0, ZERO_FLOATS * sizeof(float), stream);

    // XtX partials staged in out[] (dead until reduce consumes them)
    gram_kernel<<<dim3(GRAM_BLKS, NB), 256, 0, stream>>>(bases, targets, ws, out);
    reduce_kernel<<<dim3(16, NB), 256, 0, stream>>>(out, ws);
    solve_kernel<<<NB, 64, 0, stream>>>(ws, out);
    predvar_kernel<<<dim3(HW / 512, NB), 256, 0, stream>>>(bases, ws, out);
}

// Round 5
// 611.726 us; speedup vs baseline: 1.2337x; 1.2337x over previous
//
#include <hip/hip_runtime.h>
#include <cmath>

#define HW 307200        // 480*640
#define NB 8             // batches
#define NBASE 63         // input basis channels (ones channel prepended -> 64)
#define NSLAB (HW/64)    // 4800 slabs of 64 px
#define GRAM_BLKS 128    // 128*8 = 1024 blocks = 4 per CU

// ---- workspace layout (floats) ----
#define XTY_OFF 0                        // 8 * 64
#define YTY_OFF (NB*64)                  // 8
#define NC_OFF  (YTY_OFF + NB)           // 8
#define ZERO_FLOATS (NC_OFF + NB)        // atomic-accumulated region ends here (528)
#define XTX_OFF ZERO_FLOATS              // 8 * 64*64 (written whole by reduce_kernel)
#define MP_OFF  (XTX_OFF + NB*64*64)     // 8 * 64*64 (upper-tri M, diag halved, /beta)
#define WV_OFF  (MP_OFF + NB*64*64)      // 8 * 64

// ---- output layout (floats) ----
#define OUT_W   (NB*HW)                  // weights after logits
#define OUT_VAR (OUT_W + NB*64)          // var after weights
// NOTE: gram partials (8*128*4096 floats = 16.8MB) are staged in out[], consumed
// by reduce_kernel BEFORE solve/predvar overwrite out. Stream-ordered.

__device__ __forceinline__ bool finitef(float x) {
    // fast-math-proof isfinite: exponent bits not all ones
    return (__float_as_uint(x) & 0x7f800000u) != 0x7f800000u;
}

// ============================================================
// Kernel 1: sparse masked Gram, STREAMING fetch + register-ballot
// compaction. Slab = 64 px. Thread (quad qq = t&15, chan c = t>>4)
// streams its quad's channels {c, c+16, c+32, c+48} as float4
// (16-lane-contiguous 256B, ascending addresses -> full HBM BW).
// Validity from 4 ballots of quad targets -> identical masks in every
// wave -> slot prefix computed IN REGISTERS (no LDS, no barrier).
// Valid pixels (~5%) scatter into a 128-row LDS ring; every 64
// accumulated rows, 2 barriers + dense 8x8 outer-product tile.
// Ring safety: pending<=63 before a slab, vc<=64 -> pending<=127<128.
// Per-wave accs LDS-reduced; one coalesced 16KB partial per block.
// ============================================================
__global__ __launch_bounds__(256, 4) void gram_kernel(
    const float* __restrict__ bases, const float* __restrict__ targets,
    float* __restrict__ ws, float* __restrict__ part)
{
    __shared__ float tile[128*68];  // ring [row][channel], stride 68
    __shared__ float sy[128];       // y per ring row

    const int t  = threadIdx.x;
    const int b  = blockIdx.y;
    const int wv = t >> 6;          // wave id 0..3
    const int l  = t & 63;          // lane
    const int ti = l >> 3, tj = l & 7;
    const int qq = t & 15;          // pixel quad within slab (pixels 4qq..4qq+3)
    const int c  = t >> 4;          // channel slot 0..15 (channels c+16k)

    float acc[8][8];
#pragma unroll
    for (int i = 0; i < 8; i++)
#pragma unroll
        for (int j = 0; j < 8; j++) acc[i][j] = 0.f;
    float acc_xty = 0.f, acc_yty = 0.f, acc_n = 0.f;

    const float* __restrict__ basesb = bases + (long)b * NBASE * HW;
    const float* __restrict__ targb  = targets + (long)b * HW;

    auto compute_tile = [&](int base) {
#pragma unroll 2
        for (int pp = 0; pp < 16; ++pp) {
            const int p2 = base + wv * 16 + pp;
            const float4 r0 = *(const float4*)&tile[p2*68 + 8*ti];
            const float4 r1 = *(const float4*)&tile[p2*68 + 8*ti + 4];
            const float4 c0 = *(const float4*)&tile[p2*68 + 8*tj];
            const float4 c1 = *(const float4*)&tile[p2*68 + 8*tj + 4];
            const float rr[8] = {r0.x,r0.y,r0.z,r0.w,r1.x,r1.y,r1.z,r1.w};
            const float cc[8] = {c0.x,c0.y,c0.z,c0.w,c1.x,c1.y,c1.z,c1.w};
#pragma unroll
            for (int i = 0; i < 8; i++)
#pragma unroll
                for (int j = 0; j < 8; j++)
                    acc[i][j] = fmaf(rr[i], cc[j], acc[i][j]);
            // Xty: lane l owns channel l
            acc_xty = fmaf(sy[p2], tile[p2*68 + l], acc_xty);
        }
    };

    int fill = 0, comp = 0;         // enqueued / computed valid-pixel counts (uniform)

    for (int s = blockIdx.x; s < NSLAB; s += GRAM_BLKS) {
        const int pix0 = s * 64;
        // ---- targets for this thread's quad (all waves: same 16 quads, L1-hot) ----
        const float4 ty = *(const float4*)&targb[pix0 + 4*qq];
        const bool f0 = finitef(ty.x), f1 = finitef(ty.y);
        const bool f2 = finitef(ty.z), f3 = finitef(ty.w);
        // wave-uniform 16-bit masks (bit q = validity of pixel 4q+i)
        const unsigned M0 = (unsigned)__ballot(f0) & 0xFFFFu;
        const unsigned M1 = (unsigned)__ballot(f1) & 0xFFFFu;
        const unsigned M2 = (unsigned)__ballot(f2) & 0xFFFFu;
        const unsigned M3 = (unsigned)__ballot(f3) & 0xFFFFu;
        const int vc = __popc(M0) + __popc(M1) + __popc(M2) + __popc(M3);

        if (vc) {
            // slots: compact order = (quad, then pixel-within-quad)
            const unsigned lowq = (1u << qq) - 1u;
            const int pre = __popc(M0 & lowq) + __popc(M1 & lowq)
                          + __popc(M2 & lowq) + __popc(M3 & lowq);
            const int s0 = fill + pre;
            const int s1 = s0 + (int)((M0 >> qq) & 1u);
            const int s2 = s1 + (int)((M1 >> qq) & 1u);
            const int s3 = s2 + (int)((M2 >> qq) & 1u);

            // yty/N: one thread per quad (wave 0, lanes 0..15)
            if (t < 16) {
                if (f0) { acc_yty = fmaf(ty.x, ty.x, acc_yty); acc_n += 1.f; }
                if (f1) { acc_yty = fmaf(ty.y, ty.y, acc_yty); acc_n += 1.f; }
                if (f2) { acc_yty = fmaf(ty.z, ty.z, acc_yty); acc_n += 1.f; }
                if (f3) { acc_yty = fmaf(ty.w, ty.w, acc_yty); acc_n += 1.f; }
            }

            // ---- streaming loads: channels c+16k for this quad ----
            float4 v[4];
#pragma unroll
            for (int k = 0; k < 4; k++) {
                const int cb = c + 16*k;
                if (cb < 63)
                    v[k] = *(const float4*)&basesb[(long)cb * HW + pix0 + 4*qq];
            }
            // ---- predicated scatter of valid pixels into the ring ----
#pragma unroll
            for (int i = 0; i < 4; i++) {
                const bool fi = (i == 0) ? f0 : (i == 1) ? f1 : (i == 2) ? f2 : f3;
                if (fi) {
                    const int si  = (i == 0) ? s0 : (i == 1) ? s1 : (i == 2) ? s2 : s3;
                    const int row = si & 127;
#pragma unroll
                    for (int k = 0; k < 4; k++) {
                        const int cb = c + 16*k;
                        if (cb < 63) {
                            const float vi = (i == 0) ? v[k].x : (i == 1) ? v[k].y
                                           : (i == 2) ? v[k].z : v[k].w;
                            tile[row*68 + cb + 1] = vi;
                        }
                    }
                    if (c == 15) {  // cb==63 slot: ones channel + y
                        tile[row*68] = 1.f;
                        sy[row] = (i == 0) ? ty.x : (i == 1) ? ty.y
                                : (i == 2) ? ty.z : ty.w;
                    }
                }
            }
            fill += vc;
        } else {
            // still stream the slab (keeps fetch sequential & prefetch-friendly)
            // -> actually skip: invalid-only slabs contribute nothing; the HBM
            // cost of skipping is at line granularity and these slabs are rare
            // at 5% density (P(all 64 invalid) ~ 3.7%). No loads issued.
        }

        if (fill - comp >= 64) {
            __syncthreads();                 // scatters visible to all
            compute_tile(comp & 127);        // base 0 or 64
            comp += 64;
            __syncthreads();                 // reads done before later scatters
        }
    }

    // ---- final flush: zero-pad rows [fill, comp+ceil(pending/64)*64) ----
    const int pending = fill - comp;
    if (pending > 0) {
        const int padto = comp + ((pending + 63) & ~63);
        for (int rr = fill + wv; rr < padto; rr += 4) {
            const int row = rr & 127;
            tile[row*68 + l] = 0.f;
            if (l == 0) sy[row] = 0.f;
        }
        __syncthreads();
        for (int base = comp; base < padto; base += 64) {
            compute_tile(base & 127);
            __syncthreads();
        }
    }
    __syncthreads();

    // ---- cross-wave reduce of acc tiles into tile[0..4096) ----
    for (int w = 0; w < 4; ++w) {
        if (wv == w) {
#pragma unroll
            for (int i = 0; i < 8; i++)
#pragma unroll
                for (int j2 = 0; j2 < 8; j2++) {
                    const int e = (8*ti + i) * 64 + 8*tj + j2;
                    tile[e] = (w == 0) ? acc[i][j2] : tile[e] + acc[i][j2];
                }
        }
        __syncthreads();
    }
    // one coalesced 16KB partial per block, no atomics
    float* __restrict__ pb = part + (long)(b * GRAM_BLKS + blockIdx.x) * 4096;
#pragma unroll
    for (int k = 0; k < 4; ++k)
        *(float4*)&pb[t*16 + 4*k] = *(const float4*)&tile[t*16 + 4*k];

    // Xty: cross-wave reduce into tile[4096..4160), then 64 atomics/block
    for (int w = 0; w < 4; ++w) {
        if (wv == w) tile[4096 + l] = (w == 0) ? acc_xty : tile[4096 + l] + acc_xty;
        __syncthreads();
    }
    if (t < 64) atomicAdd(&ws[XTY_OFF + b*64 + t], tile[4096 + t]);

    // yty, N: wave shuffle reduce + one atomic per wave (only wave 0 nonzero)
#pragma unroll
    for (int off = 32; off; off >>= 1) {
        acc_yty += __shfl_down(acc_yty, off, 64);
        acc_n   += __shfl_down(acc_n,   off, 64);
    }
    if (l == 0) {
        atomicAdd(&ws[YTY_OFF + b], acc_yty);
        atomicAdd(&ws[NC_OFF  + b], acc_n);
    }
}

// ============================================================
// Kernel 1b: sum the 128 per-block XtX partials -> ws (coalesced)
// ============================================================
__global__ __launch_bounds__(256) void reduce_kernel(
    const float* __restrict__ part, float* __restrict__ ws)
{
    const int b = blockIdx.y;
    const int e = blockIdx.x * 256 + threadIdx.x;   // grid.x = 16 -> e in [0,4096)
    const float* __restrict__ pb = part + (long)b * GRAM_BLKS * 4096 + e;
    float s = 0.f;
#pragma unroll 8
    for (int k = 0; k < GRAM_BLKS; ++k)
        s += pb[(long)k * 4096];
    ws[XTX_OFF + b*4096 + e] = s;
}

// ============================================================
// Kernel 2: per batch, 64 threads = 1 wave (barriers ~free).
// Cholesky in LDS; explicit inverse with the W-column held in 64
// REGISTERS (fully unrolled, static indices); one reciprocal per
// row. Mp emitted by COLUMN (thread t = column t, coalesced).
// ============================================================
__global__ __launch_bounds__(64) void solve_kernel(
    float* __restrict__ ws, float* __restrict__ out)
{
    __shared__ float A[64*65];
    __shared__ float d0[64], dinv_s[64], xty_s[64], wv_s[64];

    const int b = blockIdx.x;
    const int t = threadIdx.x;
    const float* XtX = ws + XTX_OFF + b * 4096;

    for (int e = t; e < 4096; e += 64)
        A[(e >> 6) * 65 + (e & 63)] = XtX[e];
    xty_s[t] = ws[XTY_OFF + b*64 + t];
    const float yty = ws[YTY_OFF + b];
    const float Nc  = ws[NC_OFF  + b];
    __syncthreads();
    d0[t] = A[t*65 + t];
    __syncthreads();

    // Cholesky (lower), upper triangle keeps original XtX
    for (int k = 0; k < 64; k++) {
        const float akk = A[k*65 + k];
        __syncthreads();
        const float dk = sqrtf(akk);
        if (t == k)      A[k*65 + k] = dk;
        else if (t > k)  A[t*65 + k] /= dk;
        __syncthreads();
        if (t > k) {
            const float ltk = A[t*65 + k];
            for (int j = k + 1; j <= t; j++)
                A[t*65 + j] -= ltk * A[j*65 + k];
        }
        __syncthreads();
    }

    dinv_s[t] = 1.f / A[t*65 + t];
    __syncthreads();

    // W = (L L^T)^-1, column t in registers
    float Wc[64];
#pragma unroll
    for (int i = 0; i < 64; i++) {
        float s0 = (i == t) ? 1.f : 0.f, s1 = 0.f, s2 = 0.f, s3 = 0.f;
        const int nfull = i >> 2;
#pragma unroll
        for (int qd = 0; qd < nfull; qd++) {
            const int j = qd * 4;
            s0 = fmaf(-A[i*65 + j    ], Wc[j    ], s0);
            s1 = fmaf(-A[i*65 + j + 1], Wc[j + 1], s1);
            s2 = fmaf(-A[i*65 + j + 2], Wc[j + 2], s2);
            s3 = fmaf(-A[i*65 + j + 3], Wc[j + 3], s3);
        }
#pragma unroll
        for (int j = nfull * 4; j < i; j++)
            s0 = fmaf(-A[i*65 + j], Wc[j], s0);
        Wc[i] = ((s0 + s1) + (s2 + s3)) * dinv_s[i];
    }
#pragma unroll
    for (int i = 63; i >= 0; i--) {
        float s0 = Wc[i], s1 = 0.f, s2 = 0.f, s3 = 0.f;
        const int j0 = i + 1;
        const int nfull = (64 - j0) >> 2;
#pragma unroll
        for (int qd = 0; qd < nfull; qd++) {
            const int j = j0 + qd * 4;
            s0 = fmaf(-A[(j    )*65 + i], Wc[j    ], s0);
            s1 = fmaf(-A[(j + 1)*65 + i], Wc[j + 1], s1);
            s2 = fmaf(-A[(j + 2)*65 + i], Wc[j + 2], s2);
            s3 = fmaf(-A[(j + 3)*65 + i], Wc[j + 3], s3);
        }
#pragma unroll
        for (int j = j0 + nfull * 4; j < 64; j++)
            s0 = fmaf(-A[j*65 + i], Wc[j], s0);
        Wc[i] = ((s0 + s1) + (s2 + s3)) * dinv_s[i];
    }

    // w_t = sum_j W[j][t] * xty[j]  (= (W xty)_t, W symmetric)
    float w0 = 0.f, w1 = 0.f, w2 = 0.f, w3 = 0.f;
#pragma unroll
    for (int j = 0; j < 64; j += 4) {
        w0 = fmaf(Wc[j    ], xty_s[j    ], w0);
        w1 = fmaf(Wc[j + 1], xty_s[j + 1], w1);
        w2 = fmaf(Wc[j + 2], xty_s[j + 2], w2);
        w3 = fmaf(Wc[j + 3], xty_s[j + 3], w3);
    }
    const float wt = (w0 + w1) + (w2 + w3);
    wv_s[t] = wt;
    __syncthreads();

    // E_d = yty - 2 w.Xty + w.(XtX w)  (XtX from upper triangle + saved diag)
    float qt = 0.f;
#pragma unroll
    for (int j = 0; j < 64; j++) {
        const float x = (j > t) ? A[t*65 + j] : ((j == t) ? d0[t] : A[j*65 + t]);
        qt = fmaf(x, wv_s[j], qt);
    }
    float r1 = wt * xty_s[t];
    float r2 = wt * qt;
#pragma unroll
    for (int off = 32; off; off >>= 1) {
        r1 += __shfl_down(r1, off, 64);
        r2 += __shfl_down(r2, off, 64);
    }
    r1 = __shfl(r1, 0, 64);
    r2 = __shfl(r2, 0, 64);
    const float E_d = yty - 2.f * r1 + r2;

    // EM beta loop (uniform on all lanes), faithful to reference latch order
    float beta0 = sqrtf(Nc);
    float beta  = beta0;
    bool  done  = false;
#pragma unroll
    for (int it = 0; it < 5; ++it) {
        const float Tr_d = 64.f / beta;
        const float beta_new = Nc / (E_d + Tr_d);
        const bool conv = fabsf(beta_new / beta0 - 1.f) < 0.02f;
        if (!done) { beta = beta_new; beta0 = beta_new; }
        done = done || conv;
    }
    const float ib = 1.f / beta;

    out[OUT_W + b*64 + t] = wt;
    ws[WV_OFF + b*64 + t] = wt;
    // Mp[row j][col t]: zero below diag, 0.5x diag, * 1/beta. Coalesced column write.
    float* __restrict__ Mp = ws + MP_OFF + b * 4096;
#pragma unroll
    for (int j = 0; j < 64; j++) {
        const float v = (j > t) ? 0.f : ((j == t) ? 0.5f : 1.f) * Wc[j] * ib;
        Mp[j*64 + t] = v;
    }
}

// ============================================================
// Kernel 3: 2 pixels/thread: pred = w.b, var = 2*sum_i b_i*sum_{j>=i} Mp[i][j] b_j
// Mp staged in LDS (16KB), wave-uniform ds_read_b128 broadcasts.
// ============================================================
__global__ __launch_bounds__(256, 2) void predvar_kernel(
    const float* __restrict__ bases, const float* __restrict__ ws,
    float* __restrict__ out)
{
    __shared__ float Mp_s[4096];
    __shared__ float w_s[64];

    const int b = blockIdx.y;
    const int t = threadIdx.x;
    {
        const float4* __restrict__ src = (const float4*)(ws + MP_OFF + b * 4096);
        float4* dst = (float4*)Mp_s;
        for (int e = t; e < 1024; e += 256) dst[e] = src[e];
        if (t < 64) w_s[t] = ws[WV_OFF + b*64 + t];
    }
    __syncthreads();

    const int pix = (blockIdx.x * 256 + t) * 2;
    const float* basesb = bases + (long)b * NBASE * HW + pix;

    float2 bv[64];
    bv[0] = make_float2(1.f, 1.f);
#pragma unroll
    for (int c = 1; c < 64; c++)
        bv[c] = *(const float2*)&basesb[(long)(c - 1) * HW];

    float px = w_s[0], py = w_s[0];
#pragma unroll
    for (int c = 1; c < 64; c++) {
        px = fmaf(w_s[c], bv[c].x, px);
        py = fmaf(w_s[c], bv[c].y, py);
    }

    float vx = 0.f, vy = 0.f;
#pragma unroll
    for (int i = 0; i < 64; i++) {
        float sx = 0.f, sy2 = 0.f;
#pragma unroll
        for (int qd = i >> 2; qd < 16; qd++) {
            const float4 m = *(const float4*)&Mp_s[i*64 + 4*qd];
            sx  = fmaf(m.x, bv[4*qd+0].x, sx);
            sy2 = fmaf(m.x, bv[4*qd+0].y, sy2);
            sx  = fmaf(m.y, bv[4*qd+1].x, sx);
            sy2 = fmaf(m.y, bv[4*qd+1].y, sy2);
            sx  = fmaf(m.z, bv[4*qd+2].x, sx);
            sy2 = fmaf(m.z, bv[4*qd+2].y, sy2);
            sx  = fmaf(m.w, bv[4*qd+3].x, sx);
            sy2 = fmaf(m.w, bv[4*qd+3].y, sy2);
        }
        vx = fmaf(sx,  bv[i].x, vx);
        vy = fmaf(sy2, bv[i].y, vy);
    }

    *(float2*)&out[(long)b * HW + pix] = make_float2(px, py);
    *(float2*)&out[OUT_VAR + (long)b * HW + pix] = make_float2(2.f * vx, 2.f * vy);
}

extern "C" void kernel_launch(void* const* d_in, const int* in_sizes, int n_in,
                              void* d_out, int out_size, void* d_ws, size_t ws_size,
                              hipStream_t stream)
{
    const float* bases   = (const float*)d_in[0];
    const float* targets = (const float*)d_in[1];
    float* out = (float*)d_out;
    float* ws  = (float*)d_ws;

    // zero only the atomic-accumulated region (Xty/yty/N); XtX is written whole
    hipMemsetAsync(d_ws, 0, ZERO_FLOATS * sizeof(float), stream);

    // XtX partials staged in out[] (dead until reduce consumes them)
    gram_kernel<<<dim3(GRAM_BLKS, NB), 256, 0, stream>>>(bases, targets, ws, out);
    reduce_kernel<<<dim3(16, NB), 256, 0, stream>>>(out, ws);
    solve_kernel<<<NB, 64, 0, stream>>>(ws, out);
    predvar_kernel<<<dim3(HW / 512, NB), 256, 0, stream>>>(bases, ws, out);
}